// Round 3
// baseline (66.390 us; speedup 1.0000x reference)
//
#include <hip/hip_runtime.h>
#include <math.h>

// Cox partial-likelihood loss, N = 8192 (fixed by harness).
//
// risk_sum[i] = sum_j exp(theta[j]) * (survtime[j] >= survtime[i])
// loss = -mean((theta - log(risk_sum)) * censor)
//
// Round-3 design (single worker kernel + 4-byte out memset):
//   - harness re-poisons d_out to 0xAA before every timed replay, so we
//     zero the single output float with hipMemsetAsync (1 tiny fill) and
//     have each block atomicAdd(-blocksum/n) straight into d_out[0].
//     This removes round-2's dependent finalize kernel (+its launch gap)
//     and all ws usage.
//   - worker kernel unchanged from round-2's validated shape:
//     256 blocks x 1024 threads, 32 rows/block, register tile of 8 rows
//     per thread, each LDS float4 read feeds 8 accumulators.
//     VALU floor: 8192^2 pairs x 3 ops / 32768 lanes = 6144 cyc = 2.6 us.
//   - __expf/__logf instead of expf/logf (rel err ~1e-5, threshold 8.5e-2).
//
// Fixed floor (immovable): harness re-poisons the ~256 MB ws with
// fillBufferAligned (~40 us @ 6.8 TB/s) inside the timed region, plus
// ~10 us graph-replay overhead. Controllable part is only the ~7 us above.

#define TBLK 1024
#define ROWS_PER_BLK 32      // 8192 / 256 blocks
#define RPT 8                // rows per thread (register tile)
#define JP 32                // j's per thread partition (8192 / 256 partitions)

__global__ __launch_bounds__(TBLK) void cox_main(
    const float* __restrict__ theta,
    const float* __restrict__ survtime,
    const float* __restrict__ censor,
    float* __restrict__ out,              // d_out[0], pre-zeroed via memsetAsync
    int n)
{
    __shared__ float s_exp[8192];
    __shared__ float s_time[8192];

    const int tid = threadIdx.x;
    const int b   = blockIdx.x;

    // ---- stage exp(theta[]) and survtime[] into LDS ----
    const float4* th4 = (const float4*)theta;
    const float4* st4 = (const float4*)survtime;
    for (int v = tid; v < (n >> 2); v += TBLK) {
        float4 t = th4[v];
        float4 s = st4[v];
        int j = v << 2;
        s_exp[j + 0] = __expf(t.x);
        s_exp[j + 1] = __expf(t.y);
        s_exp[j + 2] = __expf(t.z);
        s_exp[j + 3] = __expf(t.w);
        s_time[j + 0] = s.x;
        s_time[j + 1] = s.y;
        s_time[j + 2] = s.z;
        s_time[j + 3] = s.w;
    }
    __syncthreads();

    // ---- register-tiled pair loop ----
    const int ig    = tid & 3;        // row group 0..3
    const int p     = tid >> 2;       // j partition 0..255
    const int row0  = ig * RPT;       // 0,8,16,24 within the block's 32 rows
    const int ibase = b * ROWS_PER_BLK;

    float ti[RPT], acc[RPT];
    #pragma unroll
    for (int r = 0; r < RPT; ++r) {
        ti[r]  = s_time[ibase + row0 + r];
        acc[r] = 0.0f;
    }

    const float4* e4 = (const float4*)s_exp  + p * (JP / 4);
    const float4* t4 = (const float4*)s_time + p * (JP / 4);
    #pragma unroll
    for (int k = 0; k < JP / 4; ++k) {
        float4 e = e4[k];
        float4 t = t4[k];
        #pragma unroll
        for (int r = 0; r < RPT; ++r) {
            float tr = ti[r];
            acc[r] += (t.x >= tr) ? e.x : 0.0f;
            acc[r] += (t.y >= tr) ? e.y : 0.0f;
            acc[r] += (t.z >= tr) ? e.z : 0.0f;
            acc[r] += (t.w >= tr) ? e.w : 0.0f;
        }
    }

    // ---- reduce 256 partials per row ----
    __syncthreads();                  // done with s_exp contents
    #pragma unroll
    for (int r = 0; r < RPT; ++r)
        s_exp[p * ROWS_PER_BLK + row0 + r] = acc[r];
    __syncthreads();

    // stage 2: 1024 threads fold 256 partials -> 32 per row
    {
        const int il = tid & 31;      // row
        const int q  = tid >> 5;      // 0..31
        float s = 0.0f;
        #pragma unroll
        for (int m = 0; m < 8; ++m)
            s += s_exp[(q * 8 + m) * ROWS_PER_BLK + il];
        s_time[q * ROWS_PER_BLK + il] = s;   // reuse s_time as scratch
    }
    __syncthreads();

    // stage 3: threads 0..31 finish their rows, lane-reduce, one atomic/block
    if (tid < ROWS_PER_BLK) {
        float rs = 0.0f;
        #pragma unroll
        for (int q = 0; q < 32; ++q)
            rs += s_time[q * ROWS_PER_BLK + tid];   // bank = tid: conflict-free

        const int i = ibase + tid;
        float contrib = (theta[i] - __logf(rs)) * censor[i];

        #pragma unroll
        for (int off = 16; off > 0; off >>= 1)
            contrib += __shfl_down(contrib, off);

        if (tid == 0)
            atomicAdd(out, -contrib / (float)n);   // device-scope by default
    }
}

extern "C" void kernel_launch(void* const* d_in, const int* in_sizes, int n_in,
                              void* d_out, int out_size, void* d_ws, size_t ws_size,
                              hipStream_t stream) {
    const float* theta    = (const float*)d_in[0];  // hazard_pred (N,1) flat
    const float* survtime = (const float*)d_in[1];
    const float* censor   = (const float*)d_in[2];
    float* out = (float*)d_out;

    const int n = in_sizes[1];                      // 8192
    const int nblocks = n / ROWS_PER_BLK;           // 256

    // d_out is 0xAA-poisoned before every timed replay: zero the 1 float.
    hipMemsetAsync(d_out, 0, sizeof(float), stream);

    cox_main<<<nblocks, TBLK, 0, stream>>>(theta, survtime, censor, out, n);
}

// Round 4
// 63.348 us; speedup vs baseline: 1.0480x; 1.0480x over previous
//
#include <hip/hip_runtime.h>
#include <math.h>

// Cox partial-likelihood loss, N = 8192 (fixed by harness).
//
// risk_sum[i] = sum_j exp(theta[j]) * (survtime[j] >= survtime[i])
// loss = -mean((theta - log(risk_sum)) * censor)
//
// Round-4 (final): measured-best round-2 structure (two kernels, no memset,
// plain stores to ws partials — 65.5 us) + micro-fixes:
//   - stage-1 partial-write swizzle s_exp[p*32 + ((row+p)&31)]:
//     round-2 layout had a 16-way LDS bank conflict on the writes
//     (lanes sharing ig hit one bank); swizzled layout is 2-way on both
//     writes and stage-2 reads (2-way aliasing is free, m136).
//   - finalize: single wave of 64 threads, one float4/lane (256 partials
//     in one coalesced load), pure shuffle reduce, no LDS, no branches.
//   - __expf/__logf (rel err ~1e-5 vs 8.5e-2 threshold).
//
// dur_us decomposition (rounds 1-3 evidence): ~39.7 us harness ws-poison
// fill (268 MB @ 6.8 TB/s, 85% HBM peak) + ~20 us restore/replay fixed
// overhead + ~5 us this kernel (VALU floor 2.6 us). Controllable headroom
// from here is ~noise (+-1 us).

#define TBLK 1024
#define ROWS_PER_BLK 32      // 8192 / 256 blocks
#define RPT 8                // rows per thread (register tile)
#define JP 32                // j's per thread partition (8192 / 256 partitions)

__global__ __launch_bounds__(TBLK) void cox_main(
    const float* __restrict__ theta,
    const float* __restrict__ survtime,
    const float* __restrict__ censor,
    float* __restrict__ block_partials,   // ws, one float per block
    int n)
{
    __shared__ float s_exp[8192];
    __shared__ float s_time[8192];

    const int tid = threadIdx.x;
    const int b   = blockIdx.x;

    // ---- stage exp(theta[]) and survtime[] into LDS ----
    const float4* th4 = (const float4*)theta;
    const float4* st4 = (const float4*)survtime;
    for (int v = tid; v < (n >> 2); v += TBLK) {
        float4 t = th4[v];
        float4 s = st4[v];
        int j = v << 2;
        s_exp[j + 0] = __expf(t.x);
        s_exp[j + 1] = __expf(t.y);
        s_exp[j + 2] = __expf(t.z);
        s_exp[j + 3] = __expf(t.w);
        s_time[j + 0] = s.x;
        s_time[j + 1] = s.y;
        s_time[j + 2] = s.z;
        s_time[j + 3] = s.w;
    }
    __syncthreads();

    // ---- register-tiled pair loop: 8 rows/thread, 32 j's/thread ----
    const int ig    = tid & 3;        // row group 0..3
    const int p     = tid >> 2;       // j partition 0..255
    const int row0  = ig * RPT;       // 0,8,16,24 within the block's 32 rows
    const int ibase = b * ROWS_PER_BLK;

    float ti[RPT], acc[RPT];
    #pragma unroll
    for (int r = 0; r < RPT; ++r) {
        ti[r]  = s_time[ibase + row0 + r];
        acc[r] = 0.0f;
    }

    const float4* e4 = (const float4*)s_exp  + p * (JP / 4);
    const float4* t4 = (const float4*)s_time + p * (JP / 4);
    #pragma unroll
    for (int k = 0; k < JP / 4; ++k) {
        float4 e = e4[k];
        float4 t = t4[k];
        #pragma unroll
        for (int r = 0; r < RPT; ++r) {
            float tr = ti[r];
            acc[r] += (t.x >= tr) ? e.x : 0.0f;
            acc[r] += (t.y >= tr) ? e.y : 0.0f;
            acc[r] += (t.z >= tr) ? e.z : 0.0f;
            acc[r] += (t.w >= tr) ? e.w : 0.0f;
        }
    }

    // ---- reduce 256 partials per row (swizzled layout, 2-way max) ----
    __syncthreads();                  // done with s_exp contents
    #pragma unroll
    for (int r = 0; r < RPT; ++r)
        s_exp[p * ROWS_PER_BLK + ((row0 + r + p) & 31)] = acc[r];
    __syncthreads();

    // stage 2: 1024 threads fold 256 partials -> 32 per row
    {
        const int il = tid & 31;      // row
        const int q  = tid >> 5;      // 0..31
        float s = 0.0f;
        #pragma unroll
        for (int m = 0; m < 8; ++m) {
            const int pp = q * 8 + m;
            s += s_exp[pp * ROWS_PER_BLK + ((il + pp) & 31)];
        }
        s_time[q * ROWS_PER_BLK + il] = s;   // reuse s_time as scratch
    }
    __syncthreads();

    // stage 3: threads 0..31 finish their rows, lane-reduce, one store/block
    if (tid < ROWS_PER_BLK) {
        float rs = 0.0f;
        #pragma unroll
        for (int q = 0; q < 32; ++q)
            rs += s_time[q * ROWS_PER_BLK + tid];   // bank = tid: conflict-free

        const int i = ibase + tid;
        float contrib = (theta[i] - __logf(rs)) * censor[i];

        #pragma unroll
        for (int off = 16; off > 0; off >>= 1)
            contrib += __shfl_down(contrib, off);

        if (tid == 0)
            block_partials[b] = contrib;    // plain store, overwrites poison
    }
}

__global__ __launch_bounds__(64) void cox_finalize(
    const float* __restrict__ partials,   // 256 floats
    float* __restrict__ out,
    int n)
{
    const int t = threadIdx.x;
    float4 v4 = ((const float4*)partials)[t];     // 64 lanes x 4 = 256
    float v = (v4.x + v4.y) + (v4.z + v4.w);
    #pragma unroll
    for (int off = 32; off > 0; off >>= 1)
        v += __shfl_down(v, off);
    if (t == 0)
        out[0] = -v / (float)n;
}

extern "C" void kernel_launch(void* const* d_in, const int* in_sizes, int n_in,
                              void* d_out, int out_size, void* d_ws, size_t ws_size,
                              hipStream_t stream) {
    const float* theta    = (const float*)d_in[0];  // hazard_pred (N,1) flat
    const float* survtime = (const float*)d_in[1];
    const float* censor   = (const float*)d_in[2];
    float* out = (float*)d_out;

    const int n = in_sizes[1];                      // 8192
    const int nblocks = n / ROWS_PER_BLK;           // 256

    float* block_partials = (float*)d_ws;           // plain stores, no init needed

    cox_main<<<nblocks, TBLK, 0, stream>>>(theta, survtime, censor,
                                           block_partials, n);
    cox_finalize<<<1, 64, 0, stream>>>(block_partials, out, n);
}